// Round 2
// baseline (648.366 us; speedup 1.0000x reference)
//
#include <hip/hip_runtime.h>

typedef __attribute__((ext_vector_type(4))) float f32x4;
typedef __attribute__((ext_vector_type(8))) __bf16 bf16x8;
typedef __attribute__((ext_vector_type(8))) unsigned short ushort8;

static __device__ __forceinline__ unsigned short f2bf(float f) {
    unsigned int u = __float_as_uint(f);
    u += 0x7fffu + ((u >> 16) & 1u);   // round-to-nearest-even
    return (unsigned short)(u >> 16);
}
static __device__ __forceinline__ bf16x8 as_bf(ushort8 v) {
    union { ushort8 u; bf16x8 b; } x; x.u = v; return x.b;
}

// ---------------------------------------------------------------------------
// GEMM: C[M,N] = A[M,K](f32) * B[K,N](f32) + bias[N]
// 128x128 tile, BK=32, 256 threads = 4 waves (2x2 of 64x64), mfma 16x16x32 bf16.
// EPI=0: scatter to per-head bf16 Q/K/V  (N=3072: [q|k|v] each 1024 = 16 heads x 64)
// EPI=1: plain fp32 C
// ---------------------------------------------------------------------------
template <int EPI>
__global__ __launch_bounds__(256, 2)
void gemm_f32in(const float* __restrict__ A, const float* __restrict__ Bm,
                const float* __restrict__ bias,
                unsigned short* __restrict__ qh, unsigned short* __restrict__ kh,
                unsigned short* __restrict__ vh,
                float* __restrict__ Cf,
                int M, int N, int K)
{
    __shared__ unsigned short As[128][40];   // row-major [m][k], pad 40 (80B stride, 16B-aligned)
    __shared__ unsigned short Bs[128][40];   // B transposed: [n][k]
    const int tid = threadIdx.x;
    const int wid = tid >> 6, lane = tid & 63;
    const int g = lane >> 4, c = lane & 15;
    const int wr = (wid >> 1) * 64, wc = (wid & 1) * 64;
    const int bm = blockIdx.x * 128, bn = blockIdx.y * 128;

    f32x4 acc[4][4] = {};

    for (int k0 = 0; k0 < K; k0 += 32) {
        __syncthreads();
        // stage A: 128x32 f32 -> bf16 LDS. 1024 float4, 4 per thread.
#pragma unroll
        for (int i = 0; i < 4; i++) {
            int idx = tid + 256 * i;
            int row = idx >> 3, c4 = (idx & 7) << 2;
            float4 v = *(const float4*)(A + (size_t)(bm + row) * K + k0 + c4);
            As[row][c4 + 0] = f2bf(v.x); As[row][c4 + 1] = f2bf(v.y);
            As[row][c4 + 2] = f2bf(v.z); As[row][c4 + 3] = f2bf(v.w);
        }
        // stage B: 32x128 f32, write transposed [n][k]
#pragma unroll
        for (int i = 0; i < 4; i++) {
            int idx = tid + 256 * i;
            int row = idx >> 5;            // k
            int c4 = (idx & 31) << 2;      // n
            float4 v = *(const float4*)(Bm + (size_t)(k0 + row) * N + bn + c4);
            Bs[c4 + 0][row] = f2bf(v.x); Bs[c4 + 1][row] = f2bf(v.y);
            Bs[c4 + 2][row] = f2bf(v.z); Bs[c4 + 3][row] = f2bf(v.w);
        }
        __syncthreads();

        bf16x8 af[4], bfr[4];
#pragma unroll
        for (int mi = 0; mi < 4; mi++)
            af[mi] = as_bf(*(const ushort8*)&As[wr + mi * 16 + c][g * 8]);
#pragma unroll
        for (int ni = 0; ni < 4; ni++)
            bfr[ni] = as_bf(*(const ushort8*)&Bs[wc + ni * 16 + c][g * 8]);
#pragma unroll
        for (int mi = 0; mi < 4; mi++)
#pragma unroll
            for (int ni = 0; ni < 4; ni++)
                acc[mi][ni] = __builtin_amdgcn_mfma_f32_16x16x32_bf16(
                    af[mi], bfr[ni], acc[mi][ni], 0, 0, 0);
    }

    // epilogue. C layout: col = lane&15, row = (lane>>4)*4 + reg
#pragma unroll
    for (int mi = 0; mi < 4; mi++) {
#pragma unroll
        for (int ni = 0; ni < 4; ni++) {
#pragma unroll
            for (int r = 0; r < 4; r++) {
                int m = bm + wr + mi * 16 + g * 4 + r;
                int n = bn + wc + ni * 16 + c;
                float val = acc[mi][ni][r] + bias[n];
                if (EPI == 0) {
                    int b = m >> 10, l = m & 1023;
                    int region = n >> 10, h = (n & 1023) >> 6, d = n & 63;
                    size_t o = ((size_t)((b * 16 + h) * 1024 + l)) * 64 + d;
                    unsigned short hv = f2bf(val);
                    if (region == 0) qh[o];
                    (region == 0 ? qh : region == 1 ? kh : vh)[o] = hv;
                } else {
                    Cf[(size_t)m * N + n] = val;
                }
            }
        }
    }
}

// ---------------------------------------------------------------------------
// Attention: block = (bh, q-tile of 64 rows), 256 threads = 4 waves,
// wave w owns q-rows [q0+16w, q0+16w+16). Two-pass online softmax with
// recompute; writes normalized attn (f32) and O (f32, [b][l][h*64+d]).
// ---------------------------------------------------------------------------
__global__ __launch_bounds__(256, 2)
void attn_kernel(const unsigned short* __restrict__ qh,
                 const unsigned short* __restrict__ kh,
                 const unsigned short* __restrict__ vh,
                 float* __restrict__ attn, float* __restrict__ o_blf)
{
    const int bh = blockIdx.x;   // b*16 + h
    const int qt = blockIdx.y;   // 0..15
    const int tid = threadIdx.x, wid = tid >> 6, lane = tid & 63;
    const int g = lane >> 4, c = lane & 15;
    const int q0 = qt * 64;

    __shared__ unsigned short Ks[64 * 64];   // [key][d], XOR-swizzled
    __shared__ unsigned short Vt[64 * 64];   // [d][key], XOR-swizzled
    __shared__ unsigned short Ps[4][16 * 64];// per-wave P [qlocal][key], swizzled

    const size_t baseKV = (size_t)bh * 1024 * 64;

    // Q fragments (hoisted): A-frag row = lane&15, k = g*8+j
    const int qrow = q0 + wid * 16 + c;
    bf16x8 qa[2];
    qa[0] = as_bf(*(const ushort8*)(qh + baseKV + (size_t)qrow * 64 + g * 8));
    qa[1] = as_bf(*(const ushort8*)(qh + baseKV + (size_t)qrow * 64 + 32 + g * 8));

    float mrow[4], lrow[4];
#pragma unroll
    for (int r = 0; r < 4; r++) { mrow[r] = -INFINITY; lrow[r] = 0.f; }
    const float scale = 0.125f;   // 1/sqrt(64)

    // ---- pass 1: row stats ----
    for (int kt = 0; kt <= qt; ++kt) {
        __syncthreads();
#pragma unroll
        for (int i = 0; i < 2; i++) {
            int cidx = tid + 256 * i;              // 512 chunks of 16B
            int row = cidx >> 3, col16 = cidx & 7;
            ushort8 v = *(const ushort8*)(kh + baseKV + (size_t)(kt * 64 + row) * 64 + col16 * 8);
            int off = row * 128 + ((col16 * 16) ^ ((row & 7) << 4));
            *(ushort8*)((char*)Ks + off) = v;
        }
        __syncthreads();

        f32x4 s[4];
#pragma unroll
        for (int ni = 0; ni < 4; ni++) {
            f32x4 a = {0.f, 0.f, 0.f, 0.f};
            int krow = ni * 16 + c;
#pragma unroll
            for (int ks = 0; ks < 2; ks++) {
                int off = krow * 128 + ((ks * 64 + g * 16) ^ ((krow & 7) << 4));
                bf16x8 kb = as_bf(*(const ushort8*)((const char*)Ks + off));
                a = __builtin_amdgcn_mfma_f32_16x16x32_bf16(qa[ks], kb, a, 0, 0, 0);
            }
            s[ni] = a;
        }
#pragma unroll
        for (int ni = 0; ni < 4; ni++) {
            int kcol = kt * 64 + ni * 16 + c;
#pragma unroll
            for (int r = 0; r < 4; r++) {
                int qr = q0 + wid * 16 + g * 4 + r;
                float v = s[ni][r] * scale;
                s[ni][r] = (kcol > qr) ? -1e9f : v;
            }
        }
#pragma unroll
        for (int r = 0; r < 4; r++) {
            float mx = fmaxf(fmaxf(s[0][r], s[1][r]), fmaxf(s[2][r], s[3][r]));
#pragma unroll
            for (int d = 1; d < 16; d <<= 1) mx = fmaxf(mx, __shfl_xor(mx, d));
            float nm = fmaxf(mrow[r], mx);
            float sum = __expf(s[0][r] - nm) + __expf(s[1][r] - nm) +
                        __expf(s[2][r] - nm) + __expf(s[3][r] - nm);
#pragma unroll
            for (int d = 1; d < 16; d <<= 1) sum += __shfl_xor(sum, d);
            lrow[r] = lrow[r] * __expf(mrow[r] - nm) + sum;
            mrow[r] = nm;
        }
    }
    float rinv[4];
#pragma unroll
    for (int r = 0; r < 4; r++) rinv[r] = 1.f / lrow[r];

    // ---- pass 2: write attn + accumulate O ----
    f32x4 oacc[4] = {};
    float* attnB = attn + (size_t)bh * 1024 * 1024;
    for (int kt = 0; kt <= qt; ++kt) {
        __syncthreads();
#pragma unroll
        for (int i = 0; i < 2; i++) {
            int cidx = tid + 256 * i;
            int row = cidx >> 3, col16 = cidx & 7;
            ushort8 v = *(const ushort8*)(kh + baseKV + (size_t)(kt * 64 + row) * 64 + col16 * 8);
            int off = row * 128 + ((col16 * 16) ^ ((row & 7) << 4));
            *(ushort8*)((char*)Ks + off) = v;
        }
#pragma unroll
        for (int i = 0; i < 2; i++) {
            int cidx = tid + 256 * i;
            int row = cidx >> 3, col16 = cidx & 7;   // row = key, d0 = col16*8
            ushort8 v = *(const ushort8*)(vh + baseKV + (size_t)(kt * 64 + row) * 64 + col16 * 8);
#pragma unroll
            for (int j = 0; j < 8; j++) {
                int d = col16 * 8 + j;
                int off = d * 128 + ((row * 2) ^ ((d & 7) << 4));
                *(unsigned short*)((char*)Vt + off) = v[j];
            }
        }
        __syncthreads();

        f32x4 s[4];
#pragma unroll
        for (int ni = 0; ni < 4; ni++) {
            f32x4 a = {0.f, 0.f, 0.f, 0.f};
            int krow = ni * 16 + c;
#pragma unroll
            for (int ks = 0; ks < 2; ks++) {
                int off = krow * 128 + ((ks * 64 + g * 16) ^ ((krow & 7) << 4));
                bf16x8 kb = as_bf(*(const ushort8*)((const char*)Ks + off));
                a = __builtin_amdgcn_mfma_f32_16x16x32_bf16(qa[ks], kb, a, 0, 0, 0);
            }
            s[ni] = a;
        }
        // P = exp(S*scale - m)/l ; write attn + Ps (bf16)
#pragma unroll
        for (int ni = 0; ni < 4; ni++) {
            int kcol = kt * 64 + ni * 16 + c;
#pragma unroll
            for (int r = 0; r < 4; r++) {
                int qlr = g * 4 + r;                  // local row in wave (0..15)
                int qr = q0 + wid * 16 + qlr;
                float sv = (kcol > qr) ? -1e9f : s[ni][r] * scale;
                float p = __expf(sv - mrow[r]) * rinv[r];
                attnB[(size_t)qr * 1024 + kcol] = p;
                int pcol = ni * 16 + c;
                int off = wid * 2048 + qlr * 128 + ((pcol * 2) ^ ((qlr & 7) << 4));
                *(unsigned short*)((char*)Ps + off) = f2bf(p);
            }
        }
        // PV: O[16q][64d] += P[16q][64k] @ V[64k][64d]  (same-wave LDS RAW, in-order)
#pragma unroll
        for (int ks = 0; ks < 2; ks++) {
            int aoff = wid * 2048 + c * 128 + ((ks * 64 + g * 16) ^ ((c & 7) << 4));
            bf16x8 pa = as_bf(*(const ushort8*)((const char*)Ps + aoff));
#pragma unroll
            for (int ni = 0; ni < 4; ni++) {
                int d = ni * 16 + c;
                int voff = d * 128 + ((ks * 64 + g * 16) ^ ((d & 7) << 4));
                bf16x8 vb = as_bf(*(const ushort8*)((const char*)Vt + voff));
                oacc[ni] = __builtin_amdgcn_mfma_f32_16x16x32_bf16(pa, vb, oacc[ni], 0, 0, 0);
            }
        }
    }

    // zero the strictly-upper k-tiles (d_out is poisoned; must write everything)
    {
        float4 z = {0.f, 0.f, 0.f, 0.f};
        float* zb = attnB + (size_t)q0 * 1024;
        for (int kt = qt + 1; kt < 16; ++kt) {
#pragma unroll
            for (int i = 0; i < 4; i++) {
                int idx = tid + 256 * i;          // 1024 float4
                int row = idx >> 4, c4 = (idx & 15) << 2;
                *(float4*)(zb + (size_t)row * 1024 + kt * 64 + c4) = z;
            }
        }
    }

    // write O in [b][l][h*64+d] f32 layout for the projection GEMM
    const int b = bh >> 4, h = bh & 15;
#pragma unroll
    for (int ni = 0; ni < 4; ni++) {
#pragma unroll
        for (int r = 0; r < 4; r++) {
            int qr = q0 + wid * 16 + g * 4 + r;
            int d = ni * 16 + c;
            o_blf[((size_t)(b * 1024 + qr)) * 1024 + h * 64 + d] = oacc[ni][r];
        }
    }
}

// ---------------------------------------------------------------------------
// LayerNorm(y + x) -> out.  One block (256 thr) per row of 1024.
// ---------------------------------------------------------------------------
__global__ __launch_bounds__(256, 2)
void ln_kernel(const float* __restrict__ y, const float* __restrict__ x,
               const float* __restrict__ gamma, const float* __restrict__ beta,
               float* __restrict__ out)
{
    const int m = blockIdx.x;
    const int tid = threadIdx.x;
    const int wid = tid >> 6, lane = tid & 63;
    float4 vy = *(const float4*)(y + (size_t)m * 1024 + tid * 4);
    float4 vx = *(const float4*)(x + (size_t)m * 1024 + tid * 4);
    float4 v = {vy.x + vx.x, vy.y + vx.y, vy.z + vx.z, vy.w + vx.w};
    float s1 = v.x + v.y + v.z + v.w;
    float s2 = v.x * v.x + v.y * v.y + v.z * v.z + v.w * v.w;
#pragma unroll
    for (int d = 1; d < 64; d <<= 1) {
        s1 += __shfl_xor(s1, d);
        s2 += __shfl_xor(s2, d);
    }
    __shared__ float red1[4], red2[4];
    if (lane == 0) { red1[wid] = s1; red2[wid] = s2; }
    __syncthreads();
    float t1 = red1[0] + red1[1] + red1[2] + red1[3];
    float t2 = red2[0] + red2[1] + red2[2] + red2[3];
    float mean = t1 * (1.f / 1024.f);
    float var = t2 * (1.f / 1024.f) - mean * mean;
    float rstd = rsqrtf(var + 1e-5f);
    float4 g4 = *(const float4*)(gamma + tid * 4);
    float4 b4 = *(const float4*)(beta + tid * 4);
    float4 o;
    o.x = g4.x * (v.x - mean) * rstd + b4.x;
    o.y = g4.y * (v.y - mean) * rstd + b4.y;
    o.z = g4.z * (v.z - mean) * rstd + b4.z;
    o.w = g4.w * (v.w - mean) * rstd + b4.w;
    *(float4*)(out + (size_t)m * 1024 + tid * 4) = o;
}

// ---------------------------------------------------------------------------
extern "C" void kernel_launch(void* const* d_in, const int* in_sizes, int n_in,
                              void* d_out, int out_size, void* d_ws, size_t ws_size,
                              hipStream_t stream)
{
    const float* x      = (const float*)d_in[0];
    // d_in[1] = mask (causal tril) — implemented analytically
    const float* W_qkv  = (const float*)d_in[2];
    const float* b_qkv  = (const float*)d_in[3];
    const float* W_proj = (const float*)d_in[4];
    const float* b_proj = (const float*)d_in[5];
    const float* gamma  = (const float*)d_in[6];
    const float* beta   = (const float*)d_in[7];

    float* out  = (float*)d_out;
    float* attn = out + (size_t)8 * 1024 * 1024;     // [B][H][L][L]

    unsigned short* qh = (unsigned short*)d_ws;          // [B][H][L][64] bf16
    unsigned short* kh = qh + (size_t)8 * 16 * 1024 * 64;
    unsigned short* vh = kh + (size_t)8 * 16 * 1024 * 64;
    float* o_blf = (float*)(vh + (size_t)8 * 16 * 1024 * 64);  // [8192][1024] f32
    float* yb    = o_blf + (size_t)8192 * 1024;                // [8192][1024] f32

    gemm_f32in<0><<<dim3(64, 24), 256, 0, stream>>>(
        x, W_qkv, b_qkv, qh, kh, vh, nullptr, 8192, 3072, 1024);
    attn_kernel<<<dim3(128, 16), 256, 0, stream>>>(qh, kh, vh, attn, o_blf);
    gemm_f32in<1><<<dim3(64, 8), 256, 0, stream>>>(
        o_blf, W_proj, b_proj, nullptr, nullptr, nullptr, yb, 8192, 1024, 1024);
    ln_kernel<<<8192, 256, 0, stream>>>(yb, x, gamma, beta, out);
}

// Round 3
// 304.218 us; speedup vs baseline: 2.1313x; 2.1313x over previous
//
#include <hip/hip_runtime.h>

typedef __attribute__((ext_vector_type(4))) float f32x4;
typedef __attribute__((ext_vector_type(8))) __bf16 bf16x8;
typedef __attribute__((ext_vector_type(8))) unsigned short ushort8;

static __device__ __forceinline__ unsigned short f2bf(float f) {
    unsigned int u = __float_as_uint(f);
    u += 0x7fffu + ((u >> 16) & 1u);   // round-to-nearest-even
    return (unsigned short)(u >> 16);
}
static __device__ __forceinline__ float bf2f(unsigned short u) {
    return __uint_as_float((unsigned int)u << 16);
}
static __device__ __forceinline__ bf16x8 as_bf(ushort8 v) {
    union { ushort8 u; bf16x8 b; } x; x.u = v; return x.b;
}
// async global->LDS, 16B per lane. LDS dest = wave-uniform base + lane*16.
static __device__ __forceinline__ void gll16(const void* g, void* l) {
    __builtin_amdgcn_global_load_lds(
        (const __attribute__((address_space(1))) void*)g,
        (__attribute__((address_space(3))) void*)l, 16, 0, 0);
}

// ---------------------------------------------------------------------------
// f32 -> bf16 convert (8 elems/thread)
// ---------------------------------------------------------------------------
__global__ void cvt_bf16(const float* __restrict__ in, unsigned short* __restrict__ out,
                         int n8) {
    int i = blockIdx.x * 256 + threadIdx.x;
    if (i >= n8) return;
    const float4* p = (const float4*)(in + (size_t)i * 8);
    float4 a = p[0], b = p[1];
    ushort8 o = { f2bf(a.x), f2bf(a.y), f2bf(a.z), f2bf(a.w),
                  f2bf(b.x), f2bf(b.y), f2bf(b.z), f2bf(b.w) };
    *(ushort8*)(out + (size_t)i * 8) = o;
}

// ---------------------------------------------------------------------------
// transpose + convert: in [K][N] f32 -> out [N][K] bf16. 64x64 tiles.
// ---------------------------------------------------------------------------
__global__ void tconv_bf16(const float* __restrict__ in, unsigned short* __restrict__ out,
                           int K, int N) {
    __shared__ float t[64][65];          // 65: stride%32==1 -> <=2-way on col reads
    const int tid = threadIdx.x;
    const int n0 = blockIdx.x * 64, k0 = blockIdx.y * 64;
#pragma unroll
    for (int i = 0; i < 4; i++) {
        int idx = tid + 256 * i;         // 1024 float4
        int r = idx >> 4, c4 = (idx & 15) * 4;
        float4 v = *(const float4*)(in + (size_t)(k0 + r) * N + n0 + c4);
        t[r][c4] = v.x; t[r][c4 + 1] = v.y; t[r][c4 + 2] = v.z; t[r][c4 + 3] = v.w;
    }
    __syncthreads();
#pragma unroll
    for (int i = 0; i < 2; i++) {
        int idx = tid + 256 * i;         // 512 ushort8
        int nl = idx >> 3, k8 = (idx & 7) * 8;
        ushort8 o;
#pragma unroll
        for (int j = 0; j < 8; j++) o[j] = f2bf(t[k8 + j][nl]);
        *(ushort8*)(out + (size_t)(n0 + nl) * K + k0 + k8) = o;
    }
}

// ---------------------------------------------------------------------------
// GEMM (m97-structure): C[M,N] = A[M,K](bf16) * BT[N,K](bf16)^T + bias
// 128x128 tile, BK=64, 4 waves, global_load_lds(16B) with pre-swizzled source,
// XOR-swizzled LDS reads ((row&7)<<4), XCD-aware block swizzle.
// EPI=0: scatter to per-head bf16 Q/K/V via LDS roundtrip (N=3072)
// EPI=1: plain f32 C (N passed as Ncols)
// ---------------------------------------------------------------------------
template <int EPI>
__global__ __launch_bounds__(256, 2)
void gemm_bf16(const unsigned short* __restrict__ A,
               const unsigned short* __restrict__ BT,
               const float* __restrict__ bias,
               unsigned short* __restrict__ qh, unsigned short* __restrict__ kh,
               unsigned short* __restrict__ vh,
               float* __restrict__ Cf,
               int K, int mtiles, int Ncols)
{
    __shared__ unsigned short smem[2 * 128 * 64];   // As 16KB | Bs 16KB
    unsigned short* As = smem;
    unsigned short* Bs = smem + 128 * 64;

    const int tid = threadIdx.x;
    const int wid = tid >> 6, lane = tid & 63;
    const int g = lane >> 4, c = lane & 15;
    const int wr = (wid >> 1) * 64, wc = (wid & 1) * 64;

    const int nwg = gridDim.x;
    const int swz = ((int)blockIdx.x & 7) * (nwg >> 3) + ((int)blockIdx.x >> 3);
    const int bm = (swz % mtiles) * 128;
    const int bn = (swz / mtiles) * 128;

    // staging geometry: lane covers LDS bytes [t*4096 + wid*1024 + lane*16)
    // -> row = t*32 + wid*8 + (lane>>3), 16B-slot = lane&7.
    // pre-swizzle: data for slot s must be global col-block s ^ (row&7);
    // row&7 = lane>>3  =>  source col-block = (lane&7) ^ (lane>>3).
    const int srow = lane >> 3;
    const int scol8 = ((lane & 7) ^ srow) * 8;
    const size_t arow0 = (size_t)(bm + wid * 8 + srow);
    const size_t brow0 = (size_t)(bn + wid * 8 + srow);

    f32x4 acc[4][4] = {};

    for (int k0 = 0; k0 < K; k0 += 64) {
        __syncthreads();
#pragma unroll
        for (int t = 0; t < 4; t++) {
            gll16(A + (arow0 + t * 32) * K + k0 + scol8,
                  (char*)As + t * 4096 + wid * 1024);
            gll16(BT + (brow0 + t * 32) * K + k0 + scol8,
                  (char*)Bs + t * 4096 + wid * 1024);
        }
        __syncthreads();   // compiler drains vmcnt before s_barrier
#pragma unroll
        for (int ks = 0; ks < 2; ks++) {
            bf16x8 af[4], bfr[4];
#pragma unroll
            for (int mi = 0; mi < 4; mi++) {
                int row = wr + mi * 16 + c;
                int off = row * 128 + ((ks * 64 + g * 16) ^ ((c & 7) << 4));
                af[mi] = as_bf(*(const ushort8*)((const char*)As + off));
            }
#pragma unroll
            for (int ni = 0; ni < 4; ni++) {
                int row = wc + ni * 16 + c;
                int off = row * 128 + ((ks * 64 + g * 16) ^ ((c & 7) << 4));
                bfr[ni] = as_bf(*(const ushort8*)((const char*)Bs + off));
            }
#pragma unroll
            for (int mi = 0; mi < 4; mi++)
#pragma unroll
                for (int ni = 0; ni < 4; ni++)
                    acc[mi][ni] = __builtin_amdgcn_mfma_f32_16x16x32_bf16(
                        af[mi], bfr[ni], acc[mi][ni], 0, 0, 0);
        }
    }

    if (EPI == 1) {
        // plain f32 store. C layout: col = c, row = g*4 + r.
#pragma unroll
        for (int mi = 0; mi < 4; mi++)
#pragma unroll
            for (int ni = 0; ni < 4; ni++)
#pragma unroll
                for (int r = 0; r < 4; r++) {
                    int m = bm + wr + mi * 16 + g * 4 + r;
                    int n = bn + wc + ni * 16 + c;
                    Cf[(size_t)m * Ncols + n] = acc[mi][ni][r] + bias[n];
                }
    } else {
        // QKV scatter via LDS roundtrip, two 128x64 halves (one head each).
#pragma unroll
        for (int nh = 0; nh < 2; nh++) {
            __syncthreads();
            if ((wid & 1) == nh) {
#pragma unroll
                for (int mi = 0; mi < 4; mi++)
#pragma unroll
                    for (int ni = 0; ni < 4; ni++)
#pragma unroll
                        for (int r = 0; r < 4; r++) {
                            int row = wr + mi * 16 + g * 4 + r;   // 0..127
                            int col = ni * 16 + c;                // 0..63
                            float v = acc[mi][ni][r] + bias[bn + nh * 64 + col];
                            smem[row * 64 + col] = f2bf(v);
                        }
            }
            __syncthreads();
            int n0 = bn + nh * 64;
            int region = n0 >> 10;
            int h = (n0 & 1023) >> 6;
            unsigned short* dst = region == 0 ? qh : region == 1 ? kh : vh;
#pragma unroll
            for (int i = 0; i < 4; i++) {
                int idx = tid + 256 * i;          // 1024 chunks of 16B
                int row = idx >> 3, c8 = (idx & 7) * 8;
                ushort8 v = *(const ushort8*)&smem[row * 64 + c8];
                int m = bm + row;
                int b = m >> 10, l = m & 1023;
                *(ushort8*)(dst + ((size_t)((b * 16 + h) * 1024 + l)) * 64 + c8) = v;
            }
        }
    }
}

// ---------------------------------------------------------------------------
// Attention: block = (bh, 64-row q-tile), 4 waves, wave owns 16 q-rows.
// Two-pass online softmax; K staged via global_load_lds (pre-swizzled source);
// attn written coalesced from the bf16 Ps LDS buffer; O written bf16 via LDS.
// ---------------------------------------------------------------------------
__global__ __launch_bounds__(256, 2)
void attn_kernel(const unsigned short* __restrict__ qh,
                 const unsigned short* __restrict__ kh,
                 const unsigned short* __restrict__ vh,
                 float* __restrict__ attn, unsigned short* __restrict__ ob)
{
    const int bh = blockIdx.x;   // b*16 + h
    const int qt = blockIdx.y;   // 0..15
    const int tid = threadIdx.x, wid = tid >> 6, lane = tid & 63;
    const int g = lane >> 4, c = lane & 15;
    const int q0 = qt * 64;

    __shared__ unsigned short Ks[64 * 64];   // [key][d], XOR-swizzled rows
    __shared__ unsigned short Vt[64 * 64];   // [d][key], XOR-swizzled
    __shared__ unsigned short Ps[4 * 1024];  // per-wave P [16][64], swizzled

    const size_t baseKV = (size_t)bh * (1024 * 64);

    const int qrow = q0 + wid * 16 + c;
    bf16x8 qa[2];
    qa[0] = as_bf(*(const ushort8*)(qh + baseKV + (size_t)qrow * 64 + g * 8));
    qa[1] = as_bf(*(const ushort8*)(qh + baseKV + (size_t)qrow * 64 + 32 + g * 8));

    const int srow = lane >> 3;
    const int scol8 = ((lane & 7) ^ srow) * 8;   // pre-swizzled source col-block

    float mrow[4], lrow[4];
#pragma unroll
    for (int r = 0; r < 4; r++) { mrow[r] = -INFINITY; lrow[r] = 0.f; }
    const float scale = 0.125f;

    // ---- pass 1: row stats ----
    for (int kt = 0; kt <= qt; ++kt) {
        const unsigned short* kb = kh + baseKV + (size_t)kt * 4096;
        __syncthreads();
        gll16(kb + (size_t)(wid * 8 + srow) * 64 + scol8, (char*)Ks + wid * 1024);
        gll16(kb + (size_t)(32 + wid * 8 + srow) * 64 + scol8, (char*)Ks + 4096 + wid * 1024);
        __syncthreads();

        f32x4 s[4];
#pragma unroll
        for (int ni = 0; ni < 4; ni++) {
            f32x4 a = {0.f, 0.f, 0.f, 0.f};
            int krow = ni * 16 + c;
#pragma unroll
            for (int ks = 0; ks < 2; ks++) {
                int off = krow * 128 + ((ks * 64 + g * 16) ^ ((krow & 7) << 4));
                bf16x8 kf = as_bf(*(const ushort8*)((const char*)Ks + off));
                a = __builtin_amdgcn_mfma_f32_16x16x32_bf16(qa[ks], kf, a, 0, 0, 0);
            }
            s[ni] = a;
        }
#pragma unroll
        for (int ni = 0; ni < 4; ni++) {
            int kcol = kt * 64 + ni * 16 + c;
#pragma unroll
            for (int r = 0; r < 4; r++) {
                int qr = q0 + wid * 16 + g * 4 + r;
                float v = s[ni][r] * scale;
                s[ni][r] = (kcol > qr) ? -1e9f : v;
            }
        }
#pragma unroll
        for (int r = 0; r < 4; r++) {
            float mx = fmaxf(fmaxf(s[0][r], s[1][r]), fmaxf(s[2][r], s[3][r]));
#pragma unroll
            for (int d = 1; d < 16; d <<= 1) mx = fmaxf(mx, __shfl_xor(mx, d));
            float nm = fmaxf(mrow[r], mx);
            float sum = __expf(s[0][r] - nm) + __expf(s[1][r] - nm) +
                        __expf(s[2][r] - nm) + __expf(s[3][r] - nm);
#pragma unroll
            for (int d = 1; d < 16; d <<= 1) sum += __shfl_xor(sum, d);
            lrow[r] = lrow[r] * __expf(mrow[r] - nm) + sum;
            mrow[r] = nm;
        }
    }
    float rinv[4];
#pragma unroll
    for (int r = 0; r < 4; r++) rinv[r] = 1.f / lrow[r];

    // ---- pass 2: write attn + accumulate O ----
    f32x4 oacc[4] = {};
    float* attnB = attn + (size_t)bh * (1024 * 1024);
    for (int kt = 0; kt <= qt; ++kt) {
        const unsigned short* kb = kh + baseKV + (size_t)kt * 4096;
        const unsigned short* vb = vh + baseKV + (size_t)kt * 4096;
        __syncthreads();   // protects Ks/Vt/Ps reuse from prev iteration
        gll16(kb + (size_t)(wid * 8 + srow) * 64 + scol8, (char*)Ks + wid * 1024);
        gll16(kb + (size_t)(32 + wid * 8 + srow) * 64 + scol8, (char*)Ks + 4096 + wid * 1024);
#pragma unroll
        for (int i = 0; i < 2; i++) {
            int cidx = tid + 256 * i;
            int row = cidx >> 3, col16 = cidx & 7;   // row = key, d0 = col16*8
            ushort8 v = *(const ushort8*)(vb + (size_t)row * 64 + col16 * 8);
#pragma unroll
            for (int j = 0; j < 8; j++) {
                int d = col16 * 8 + j;
                int off = d * 128 + ((row * 2) ^ ((d & 7) << 4));
                *(unsigned short*)((char*)Vt + off) = v[j];
            }
        }
        __syncthreads();

        f32x4 s[4];
#pragma unroll
        for (int ni = 0; ni < 4; ni++) {
            f32x4 a = {0.f, 0.f, 0.f, 0.f};
            int krow = ni * 16 + c;
#pragma unroll
            for (int ks = 0; ks < 2; ks++) {
                int off = krow * 128 + ((ks * 64 + g * 16) ^ ((krow & 7) << 4));
                bf16x8 kf = as_bf(*(const ushort8*)((const char*)Ks + off));
                a = __builtin_amdgcn_mfma_f32_16x16x32_bf16(qa[ks], kf, a, 0, 0, 0);
            }
            s[ni] = a;
        }
        // P = exp(S*scale - m)/l -> bf16 Ps (PV operand AND attn store source)
#pragma unroll
        for (int ni = 0; ni < 4; ni++) {
            int kcol = kt * 64 + ni * 16 + c;
#pragma unroll
            for (int r = 0; r < 4; r++) {
                int qlr = g * 4 + r;
                int qr = q0 + wid * 16 + qlr;
                float sv = (kcol > qr) ? -1e9f : s[ni][r] * scale;
                float p = __expf(sv - mrow[r]) * rinv[r];
                int pcol = ni * 16 + c;
                int off = wid * 2048 + qlr * 128 + ((pcol * 2) ^ ((qlr & 7) << 4));
                *(unsigned short*)((char*)Ps + off) = f2bf(p);
            }
        }
        // PV: same-wave LDS RAW (in-order) — O += P @ V
#pragma unroll
        for (int ks = 0; ks < 2; ks++) {
            int aoff = wid * 2048 + c * 128 + ((ks * 64 + g * 16) ^ ((c & 7) << 4));
            bf16x8 pa = as_bf(*(const ushort8*)((const char*)Ps + aoff));
#pragma unroll
            for (int ni = 0; ni < 4; ni++) {
                int d = ni * 16 + c;
                int voff = d * 128 + ((ks * 64 + g * 16) ^ ((d & 7) << 4));
                bf16x8 vf = as_bf(*(const ushort8*)((const char*)Vt + voff));
                oacc[ni] = __builtin_amdgcn_mfma_f32_16x16x32_bf16(pa, vf, oacc[ni], 0, 0, 0);
            }
        }
        __syncthreads();   // all waves' Ps complete before cooperative store
        // coalesced attn store: 64 rows x 64 cols, 2x float4 per thread
#pragma unroll
        for (int i = 0; i < 2; i++) {
            int idx = tid + 256 * i;
            int row = idx >> 3, c16 = idx & 7;
            int off = (row >> 4) * 2048 + (row & 15) * 128 + ((c16 * 16) ^ ((row & 7) << 4));
            ushort8 v = *(const ushort8*)((const char*)Ps + off);
            float4 f0 = { bf2f(v[0]), bf2f(v[1]), bf2f(v[2]), bf2f(v[3]) };
            float4 f1 = { bf2f(v[4]), bf2f(v[5]), bf2f(v[6]), bf2f(v[7]) };
            float* dp = attnB + (size_t)(q0 + row) * 1024 + kt * 64 + c16 * 8;
            *(float4*)dp = f0;
            *(float4*)(dp + 4) = f1;
        }
    }

    // zero the strictly-upper k-tiles (d_out is poisoned)
    {
        float4 z = {0.f, 0.f, 0.f, 0.f};
        float* zb = attnB + (size_t)q0 * 1024;
        for (int kt = qt + 1; kt < 16; ++kt) {
#pragma unroll
            for (int i = 0; i < 4; i++) {
                int idx = tid + 256 * i;
                int row = idx >> 4, c4 = (idx & 15) << 2;
                *(float4*)(zb + (size_t)row * 1024 + kt * 64 + c4) = z;
            }
        }
    }

    // O (bf16) via LDS roundtrip -> [b][l][h*64+d] for the projection GEMM
    __syncthreads();
#pragma unroll
    for (int ni = 0; ni < 4; ni++)
#pragma unroll
        for (int r = 0; r < 4; r++) {
            int row = wid * 16 + g * 4 + r;   // 0..63
            int d = ni * 16 + c;
            int off = row * 128 + ((d * 2) ^ ((row & 7) << 4));
            *(unsigned short*)((char*)Ks + off) = f2bf(oacc[ni][r]);
        }
    __syncthreads();
    {
        const int b = bh >> 4, h = bh & 15;
#pragma unroll
        for (int i = 0; i < 2; i++) {
            int idx = tid + 256 * i;
            int row = idx >> 3, c16 = idx & 7;
            int off = row * 128 + ((c16 * 16) ^ ((row & 7) << 4));
            ushort8 v = *(const ushort8*)((const char*)Ks + off);
            *(ushort8*)(ob + ((size_t)(b * 1024 + q0 + row)) * 1024 + h * 64 + c16 * 8) = v;
        }
    }
}

// ---------------------------------------------------------------------------
// LayerNorm(y + x) -> out
// ---------------------------------------------------------------------------
__global__ __launch_bounds__(256, 2)
void ln_kernel(const float* __restrict__ y, const float* __restrict__ x,
               const float* __restrict__ gamma, const float* __restrict__ beta,
               float* __restrict__ out)
{
    const int m = blockIdx.x;
    const int tid = threadIdx.x;
    const int wid = tid >> 6, lane = tid & 63;
    float4 vy = *(const float4*)(y + (size_t)m * 1024 + tid * 4);
    float4 vx = *(const float4*)(x + (size_t)m * 1024 + tid * 4);
    float4 v = {vy.x + vx.x, vy.y + vx.y, vy.z + vx.z, vy.w + vx.w};
    float s1 = v.x + v.y + v.z + v.w;
    float s2 = v.x * v.x + v.y * v.y + v.z * v.z + v.w * v.w;
#pragma unroll
    for (int d = 1; d < 64; d <<= 1) {
        s1 += __shfl_xor(s1, d);
        s2 += __shfl_xor(s2, d);
    }
    __shared__ float red1[4], red2[4];
    if (lane == 0) { red1[wid] = s1; red2[wid] = s2; }
    __syncthreads();
    float t1 = red1[0] + red1[1] + red1[2] + red1[3];
    float t2 = red2[0] + red2[1] + red2[2] + red2[3];
    float mean = t1 * (1.f / 1024.f);
    float var = t2 * (1.f / 1024.f) - mean * mean;
    float rstd = rsqrtf(var + 1e-5f);
    float4 g4 = *(const float4*)(gamma + tid * 4);
    float4 b4 = *(const float4*)(beta + tid * 4);
    float4 o;
    o.x = g4.x * (v.x - mean) * rstd + b4.x;
    o.y = g4.y * (v.y - mean) * rstd + b4.y;
    o.z = g4.z * (v.z - mean) * rstd + b4.z;
    o.w = g4.w * (v.w - mean) * rstd + b4.w;
    *(float4*)(out + (size_t)m * 1024 + tid * 4) = o;
}

// ---------------------------------------------------------------------------
extern "C" void kernel_launch(void* const* d_in, const int* in_sizes, int n_in,
                              void* d_out, int out_size, void* d_ws, size_t ws_size,
                              hipStream_t stream)
{
    const float* x      = (const float*)d_in[0];
    // d_in[1] = mask — causal, implemented analytically
    const float* W_qkv  = (const float*)d_in[2];
    const float* b_qkv  = (const float*)d_in[3];
    const float* W_proj = (const float*)d_in[4];
    const float* b_proj = (const float*)d_in[5];
    const float* gamma  = (const float*)d_in[6];
    const float* beta   = (const float*)d_in[7];

    float* out  = (float*)d_out;
    float* attn = out + (size_t)8 * 1024 * 1024;

    const size_t E = (size_t)8192 * 1024;            // 8388608
    unsigned short* ws = (unsigned short*)d_ws;
    unsigned short* qh     = ws;                     // bf16 [B][H][L][64]
    unsigned short* kh     = qh + E;
    unsigned short* vh     = kh + E;
    unsigned short* xb     = vh + E;                 // bf16 [8192][1024]
    unsigned short* wqkvT  = xb + E;                 // bf16 [3072][1024]
    unsigned short* wprojT = wqkvT + (size_t)3072 * 1024;  // bf16 [1024][1024]
    unsigned short* ob     = wprojT + (size_t)1024 * 1024; // bf16 [8192][1024]
    float* yb = (float*)(void*)qh;                   // overlays qh+kh (dead after attn)

    cvt_bf16<<<4096, 256, 0, stream>>>(x, xb, (int)(E / 8));
    tconv_bf16<<<dim3(48, 16), 256, 0, stream>>>(W_qkv, wqkvT, 1024, 3072);
    tconv_bf16<<<dim3(16, 16), 256, 0, stream>>>(W_proj, wprojT, 1024, 1024);

    gemm_bf16<0><<<1536, 256, 0, stream>>>(xb, wqkvT, b_qkv,
                                           qh, kh, vh, nullptr, 1024, 64, 3072);
    attn_kernel<<<dim3(128, 16), 256, 0, stream>>>(qh, kh, vh, attn, ob);
    gemm_bf16<1><<<512, 256, 0, stream>>>(ob, wprojT, b_proj,
                                          nullptr, nullptr, nullptr, yb, 1024, 64, 1024);
    ln_kernel<<<8192, 256, 0, stream>>>(yb, x, gamma, beta, out);
}